// Round 6
// baseline (485.095 us; speedup 1.0000x reference)
//
#include <hip/hip_runtime.h>
#include <hip/hip_bf16.h>

// B=16, S=2048, D=64 attention w/ symmetric pad mask.
// out = [context (B*S*D fp32), attn (B*S*S fp32)] concatenated.
//
// R6: S^T formulation. QK^T computed as K·Q^T (operands swapped) so lane
// (g,c) holds P[q=c][k=j0+g*4+r] — exactly the A-fragment of
// mfma_f32_16x16x16f16. PV fuses into pass A straight from registers
// (unnormalized; ctx scaled by 1/l at end): no sP panel, no P LDS traffic.
// Pass B recomputes S^T and stores normalized fp32 attn DIRECTLY from
// registers (lanes g=0..3 cover 64 contiguous bytes per q-row => full
// sectors). Row sums: q-row = lane's c => in-lane add + shfl_xor(16,32).
// R5 lesson: P round-tripped through global (2x134 MB) costs more than
// recomputing QK^T (~3 us matrix pipe) — two-pass recompute is right.
#define NBATCH 16
#define SLEN   2048
#define DIM    64
#define TQ     64
#define NTHR   256
#define PANEL  128
#define NPANEL (SLEN / PANEL)   // 16
#define PROWK  72               // shorts: 64 data + 8 pad
#define PROWV  134              // halfs: 128 data + 6 pad (bank stride 3 mod 32)

typedef __attribute__((ext_vector_type(8))) short bf16x8;
typedef __attribute__((ext_vector_type(4))) float f32x4;
typedef __attribute__((ext_vector_type(4))) _Float16 f16x4;

__device__ inline short f2bf(float f) {
    union { __hip_bfloat16 h; short s; } u;
    u.h = __float2bfloat16(f);
    return u.s;
}
__device__ inline bf16x8 pack8(float4 a, float4 b) {
    bf16x8 r;
    r[0] = f2bf(a.x); r[1] = f2bf(a.y); r[2] = f2bf(a.z); r[3] = f2bf(a.w);
    r[4] = f2bf(b.x); r[5] = f2bf(b.y); r[6] = f2bf(b.z); r[7] = f2bf(b.w);
    return r;
}

__global__ __launch_bounds__(NTHR, 4) void sdpa_kernel(
    const float* __restrict__ Q, const float* __restrict__ K,
    const float* __restrict__ V, const int* __restrict__ M,
    float* __restrict__ outCtx, float* __restrict__ outAttn)
{
    __shared__ __align__(16) short sK[PANEL * PROWK];      // 18.0 KB K panel bf16
    __shared__ __align__(16) _Float16 sVT[DIM * PROWV];    // 16.8 KB V^T f16 [d][k]
    __shared__ float sMask[PANEL];                         // 0/1 column mask

    const int tid = threadIdx.x;
    const int w = tid >> 6, l = tid & 63, g = l >> 4, c = l & 15;
    const int b  = blockIdx.x >> 5;          // 32 blocks/batch
    const int i0w = (blockIdx.x & 31) * TQ + w * 16;   // this wave's q-row base

    const float* Kb = K + (size_t)b * SLEN * DIM;
    const float* Vb = V + (size_t)b * SLEN * DIM;
    const int*   Mb = M + b * SLEN;

    // Q fragments (used as B-operand of K·Q^T): lane (g,c) holds
    // Q[i0w + c][g*8 .. +7] (qa0: d 0..31, qa1: d 32..63)
    bf16x8 qa0, qa1;
    {
        const float* qp = Q + ((size_t)b * SLEN + i0w + c) * DIM + g * 8;
        qa0 = pack8(*(const float4*)(qp),      *(const float4*)(qp + 4));
        qa1 = pack8(*(const float4*)(qp + 32), *(const float4*)(qp + 36));
    }
    const int rowm = Mb[i0w + c];   // this lane's q-row mask

    const float scl = 0.125f;   // 1/sqrt(64)
    float rsum0 = 0.f, rsum1 = 0.f, rsum2 = 0.f, rsum3 = 0.f;
    f32x4 pv[4];
    #pragma unroll
    for (int nt = 0; nt < 4; nt++) pv[nt] = (f32x4){0.f, 0.f, 0.f, 0.f};

    // ---- Pass A: S^T -> exp -> {rsum, fused unnormalized PV} ----
    for (int p = 0; p < NPANEL; p++) {
        const int j0 = p * PANEL;
        #pragma unroll
        for (int it = 0; it < 8; it++) {           // stage K panel 128x64 -> bf16
            const int idx = it * NTHR + tid;
            const int row = idx >> 4, c4 = idx & 15;
            float4 kv = *(const float4*)(Kb + (size_t)(j0 + row) * DIM + c4 * 4);
            *(short4*)(sK + row * PROWK + c4 * 4) =
                make_short4(f2bf(kv.x), f2bf(kv.y), f2bf(kv.z), f2bf(kv.w));
        }
        #pragma unroll
        for (int it = 0; it < 2; it++) {           // stage V^T f16 (4k x 4d transpose)
            const int task = it * NTHR + tid;
            const int kb = (task >> 4) * 4, d4 = (task & 15) * 4;
            const float* vp = Vb + (size_t)(j0 + kb) * DIM + d4;
            float4 r0 = *(const float4*)(vp);
            float4 r1 = *(const float4*)(vp + DIM);
            float4 r2 = *(const float4*)(vp + 2 * DIM);
            float4 r3 = *(const float4*)(vp + 3 * DIM);
            f16x4 t;
            t[0] = (_Float16)r0.x; t[1] = (_Float16)r1.x; t[2] = (_Float16)r2.x; t[3] = (_Float16)r3.x;
            *(f16x4*)(sVT + (d4 + 0) * PROWV + kb) = t;
            t[0] = (_Float16)r0.y; t[1] = (_Float16)r1.y; t[2] = (_Float16)r2.y; t[3] = (_Float16)r3.y;
            *(f16x4*)(sVT + (d4 + 1) * PROWV + kb) = t;
            t[0] = (_Float16)r0.z; t[1] = (_Float16)r1.z; t[2] = (_Float16)r2.z; t[3] = (_Float16)r3.z;
            *(f16x4*)(sVT + (d4 + 2) * PROWV + kb) = t;
            t[0] = (_Float16)r0.w; t[1] = (_Float16)r1.w; t[2] = (_Float16)r2.w; t[3] = (_Float16)r3.w;
            *(f16x4*)(sVT + (d4 + 3) * PROWV + kb) = t;
        }
        if (tid < PANEL) sMask[tid] = Mb[j0 + tid] ? 0.f : 1.f;
        __syncthreads();

        #pragma unroll
        for (int jt = 0; jt < 8; jt++) {
            // A-operand: K rows — lane (g,c) holds K[j0+jt*16+c][g*8..+7]
            const short* kr = sK + (jt * 16 + c) * PROWK + g * 8;
            bf16x8 kb0 = *(const bf16x8*)(kr);
            bf16x8 kb1 = *(const bf16x8*)(kr + 32);
            f32x4 acc = {0.f, 0.f, 0.f, 0.f};
            acc = __builtin_amdgcn_mfma_f32_16x16x32_bf16(kb0, qa0, acc, 0, 0, 0);
            acc = __builtin_amdgcn_mfma_f32_16x16x32_bf16(kb1, qa1, acc, 0, 0, 0);
            // lane (g,c) reg r = S[q=c][k=j0+jt*16+g*4+r]
            const float4 mv = *(const float4*)(sMask + jt * 16 + g * 4);
            const float e0 = __expf(acc[0] * scl) * mv.x;
            const float e1 = __expf(acc[1] * scl) * mv.y;
            const float e2 = __expf(acc[2] * scl) * mv.z;
            const float e3 = __expf(acc[3] * scl) * mv.w;
            rsum0 += e0; rsum1 += e1; rsum2 += e2; rsum3 += e3;
            // P regs ARE the 16x16x16 A-frag: A[m=c][k=g*4+i]
            f16x4 pfrag;
            pfrag[0] = (_Float16)e0; pfrag[1] = (_Float16)e1;
            pfrag[2] = (_Float16)e2; pfrag[3] = (_Float16)e3;
            const _Float16* vb = sVT + jt * 16 + g * 4;
            #pragma unroll
            for (int nt = 0; nt < 4; nt++) {
                f16x4 vfrag = *(const f16x4*)(vb + (nt * 16 + c) * PROWV);
                pv[nt] = __builtin_amdgcn_mfma_f32_16x16x16f16(pfrag, vfrag, pv[nt], 0, 0, 0);
            }
        }
        __syncthreads();
    }

    // ---- finalize: per-lane q-row (=c) sum; all g-copies end identical ----
    float s = rsum0 + rsum1 + rsum2 + rsum3;
    s += __shfl_xor(s, 16, 64);
    s += __shfl_xor(s, 32, 64);
    const float scv = (rowm || s <= 0.f) ? 0.f : 1.f / s;

    // ctx: D[q=g*4+r][d=nt*16+c]; fetch each row's scale via bpermute
    #pragma unroll
    for (int r = 0; r < 4; r++) {
        const float scr = __shfl(scv, g * 4 + r, 64);
        #pragma unroll
        for (int nt = 0; nt < 4; nt++)
            outCtx[((size_t)b * SLEN + i0w + g * 4 + r) * DIM + nt * 16 + c] =
                pv[nt][r] * scr;
    }

    // ---- Pass B: recompute S^T, normalize, direct fp32 attn stores ----
    float* arow = outAttn + ((size_t)b * SLEN + i0w + c) * SLEN;
    for (int p = 0; p < NPANEL; p++) {
        const int j0 = p * PANEL;
        #pragma unroll
        for (int it = 0; it < 8; it++) {           // stage K panel
            const int idx = it * NTHR + tid;
            const int row = idx >> 4, c4 = idx & 15;
            float4 kv = *(const float4*)(Kb + (size_t)(j0 + row) * DIM + c4 * 4);
            *(short4*)(sK + row * PROWK + c4 * 4) =
                make_short4(f2bf(kv.x), f2bf(kv.y), f2bf(kv.z), f2bf(kv.w));
        }
        if (tid < PANEL) sMask[tid] = Mb[j0 + tid] ? 0.f : 1.f;
        __syncthreads();

        #pragma unroll
        for (int jt = 0; jt < 8; jt++) {
            const short* kr = sK + (jt * 16 + c) * PROWK + g * 8;
            bf16x8 kb0 = *(const bf16x8*)(kr);
            bf16x8 kb1 = *(const bf16x8*)(kr + 32);
            f32x4 acc = {0.f, 0.f, 0.f, 0.f};
            acc = __builtin_amdgcn_mfma_f32_16x16x32_bf16(kb0, qa0, acc, 0, 0, 0);
            acc = __builtin_amdgcn_mfma_f32_16x16x32_bf16(kb1, qa1, acc, 0, 0, 0);
            const float4 mv = *(const float4*)(sMask + jt * 16 + g * 4);
            float4 o;
            o.x = __expf(acc[0] * scl) * mv.x * scv;
            o.y = __expf(acc[1] * scl) * mv.y * scv;
            o.z = __expf(acc[2] * scl) * mv.z * scv;
            o.w = __expf(acc[3] * scl) * mv.w * scv;
            // lanes (g=0..3, c) cover attn[q=i0w+c][j0+jt*16 .. +15]: 64 B/row
            *(float4*)(arow + j0 + jt * 16 + g * 4) = o;
        }
        __syncthreads();
    }
}

extern "C" void kernel_launch(void* const* d_in, const int* in_sizes, int n_in,
                              void* d_out, int out_size, void* d_ws, size_t ws_size,
                              hipStream_t stream) {
    const float* Q = (const float*)d_in[0];
    const float* K = (const float*)d_in[1];
    const float* V = (const float*)d_in[2];
    const int*   M = (const int*)d_in[3];
    float* outCtx  = (float*)d_out;
    float* outAttn = (float*)d_out + (size_t)NBATCH * SLEN * DIM;
    dim3 grid(NBATCH * (SLEN / TQ));   // 512 blocks
    sdpa_kernel<<<grid, NTHR, 0, stream>>>(Q, K, V, M, outCtx, outAttn);
}